// Round 4
// baseline (68.110 us; speedup 1.0000x reference)
//
#include <hip/hip_runtime.h>
#include <hip/hip_bf16.h>

// PatchExtractor3d: out[b, c*27 + i*9 + j*3 + l, d, h, w] = x_pad[b, c, d+i-1, h+j-1, w+l-1]
// x: (2, 3, 32, 128, 128) f32 ; out: (2, 81, 32, 128, 128) f32 (339.7 MB written)
//
// R3 structure: i moved to the grid (blockIdx.y = bc*3+i, 18 values) so each
// wave only touches 9 write streams (j,l channels) instead of 27; each thread
// owns 8 rows per channel (k=0..7, h=h0+2k, lane bit5 = h parity), so per
// channel a wave issues 8 back-to-back dwordx4 stores = 8KB contiguous, all
// sharing one address register. Edge shuffles hoisted per-j so store bursts
// have no interleaved lgkm waits. 17 row loads per thread serve 72 stores.

#define B_  2
#define C_  3
#define D_  32
#define H_  128
#define W_  128
#define HW_ (H_ * W_)
#define CHW ((size_t)(D_ * H_ * W_))   // 524288 floats per output channel

__global__ __launch_bounds__(256) void patch3d_kernel(const float* __restrict__ x,
                                                      float* __restrict__ out) {
    const int g  = blockIdx.y;          // bc*3 + i  (18 values, block-uniform)
    const int bc = g / 3;               // b*3 + c
    const int i  = g % 3;

    const int d     = blockIdx.x >> 1;  // 0..31
    const int hhalf = blockIdx.x & 1;   // h in [hhalf*64, hhalf*64+64)

    const int tid  = threadIdx.x;
    const int w4   = tid & 31;          // float4 index in W (32)
    const int hpar = (tid >> 5) & 1;    // lane bit 5 = h parity
    const int hq   = tid >> 6;          // wave id 0..3 -> 16-row group
    const int h0   = hhalf * 64 + hq * 16 + hpar;   // rows h0 + 2k, k=0..7

    const int  dp  = d + i - 1;
    const bool dok = (unsigned)dp < (unsigned)D_;

    const float* __restrict__ src =
        x + (size_t)bc * CHW + (size_t)(dok ? dp : 0) * HW_;

    // 17 source rows: R[m] = row (h0 - 1 + m); OOB rows (and OOB plane) -> 0
    float4 R[17];
#pragma unroll
    for (int m = 0; m < 17; ++m) {
        const int hp = h0 - 1 + m;
        float4 v = make_float4(0.f, 0.f, 0.f, 0.f);
        if (dok & ((unsigned)hp < (unsigned)H_)) {
            v = *reinterpret_cast<const float4*>(src + (size_t)hp * W_ + w4 * 4);
        }
        R[m] = v;
    }

    float* __restrict__ dst0 = out + (size_t)(bc * 27 + i * 9) * CHW
                                   + (size_t)d * HW_ + (size_t)h0 * W_ + w4 * 4;

#pragma unroll
    for (int j = 0; j < 3; ++j) {
        // hoist edge shuffles for this j's 8 rows (rows m = 2k + j)
        float le8[8], ri8[8];
#pragma unroll
        for (int k = 0; k < 8; ++k) {
            const float4 v = R[2 * k + j];
            // left = x[.., w0-1] from lane w4-1 (.w); cross-parity leak lands
            // exactly on masked w4==0 / w4==31 lanes (the pad-zero positions)
            float l_ = __shfl_up(v.w, 1, 64);
            float r_ = __shfl_down(v.x, 1, 64);
            if (w4 == 0)  l_ = 0.f;
            if (w4 == 31) r_ = 0.f;
            le8[k] = l_;  ri8[k] = r_;
        }
#pragma unroll
        for (int l = 0; l < 3; ++l) {
            float* p = dst0 + (size_t)(j * 3 + l) * CHW;
#pragma unroll
            for (int k = 0; k < 8; ++k) {
                const float4 v = R[2 * k + j];
                float4 o;
                if (l == 0)      o = make_float4(le8[k], v.x, v.y, v.z);
                else if (l == 1) o = v;
                else             o = make_float4(v.y, v.z, v.w, ri8[k]);
                // k*256 floats = 2 rows = 1KB; 8 stores cover 8KB contiguous
                *reinterpret_cast<float4*>(p + k * 256) = o;
            }
        }
    }
}

extern "C" void kernel_launch(void* const* d_in, const int* in_sizes, int n_in,
                              void* d_out, int out_size, void* d_ws, size_t ws_size,
                              hipStream_t stream) {
    const float* x = (const float*)d_in[0];
    float* out = (float*)d_out;

    // per (bc,i): 64 blocks (d x hhalf) of 256 threads; 18 (bc,i) groups
    dim3 grid(64, B_ * C_ * 3, 1);
    dim3 block(256, 1, 1);
    patch3d_kernel<<<grid, block, 0, stream>>>(x, out);
}

// Round 6
// 67.647 us; speedup vs baseline: 1.0068x; 1.0068x over previous
//
#include <hip/hip_runtime.h>
#include <hip/hip_bf16.h>

// PatchExtractor3d: out[b, c*27 + i*9 + j*3 + l, d, h, w] = x_pad[b, c, d+i-1, h+j-1, w+l-1]
// x: (2, 3, 32, 128, 128) f32 ; out: (2, 81, 32, 128, 128) f32 (339.7 MB written)
//
// R5 = R4 with the nontemporal-store type fixed (native ext_vector_type(4),
// since __builtin_nontemporal_store rejects HIP_vector_type):
//  1. nt stores: output is write-once; non-temporal hint keeps the 340MB write
//     stream from evicting the input slab out of per-XCD L2.
//  2. XCD pinning: 1D grid, dchunk = bid & 7 -> all blocks of one 4-plane
//     d-chunk land on one XCD (x-fastest round-robin). Per-XCD input working
//     set = 6 planes x 6 volumes x 64KB = 2.25MB < 4MB L2, read once.

#define B_  2
#define C_  3
#define D_  32
#define H_  128
#define W_  128
#define HW_ (H_ * W_)
#define CHW ((size_t)(D_ * H_ * W_))   // 524288 floats per output channel

typedef float f32x4 __attribute__((ext_vector_type(4)));

__global__ __launch_bounds__(256) void patch3d_kernel(const float* __restrict__ x,
                                                      float* __restrict__ out) {
    // 1D grid, 1152 blocks. bid = (rest:144) * 8 + dchunk
    // rest -> bc(6) x i(3) x hhalf(2) x dsub(4)
    const int bid    = blockIdx.x;
    const int dchunk = bid & 7;         // -> XCD (round-robin)
    const int rest   = bid >> 3;        // 0..143
    const int bc     = rest / 24;       // b*3 + c
    const int r      = rest - bc * 24;  // 0..23
    const int i      = r >> 3;          // 0..2
    const int r2     = r & 7;
    const int hhalf  = r2 >> 2;         // 0..1
    const int dsub   = r2 & 3;          // 0..3
    const int d      = dchunk * 4 + dsub;

    const int tid  = threadIdx.x;
    const int w4   = tid & 31;          // float4 index in W (32)
    const int hpar = (tid >> 5) & 1;    // lane bit 5 = h parity
    const int hq   = tid >> 6;          // wave id 0..3 -> 16-row group
    const int h0   = hhalf * 64 + hq * 16 + hpar;   // rows h0 + 2k, k=0..7

    const int  dp  = d + i - 1;
    const bool dok = (unsigned)dp < (unsigned)D_;

    const float* __restrict__ src =
        x + (size_t)bc * CHW + (size_t)(dok ? dp : 0) * HW_;

    // 17 source rows: R[m] = row (h0 - 1 + m); OOB rows (and OOB plane) -> 0
    f32x4 R[17];
#pragma unroll
    for (int m = 0; m < 17; ++m) {
        const int hp = h0 - 1 + m;
        f32x4 v = (f32x4){0.f, 0.f, 0.f, 0.f};
        if (dok & ((unsigned)hp < (unsigned)H_)) {
            v = *reinterpret_cast<const f32x4*>(src + (size_t)hp * W_ + w4 * 4);
        }
        R[m] = v;
    }

    float* __restrict__ dst0 = out + (size_t)(bc * 27 + i * 9) * CHW
                                   + (size_t)d * HW_ + (size_t)h0 * W_ + w4 * 4;

#pragma unroll
    for (int j = 0; j < 3; ++j) {
        // hoist edge shuffles for this j's 8 rows (rows m = 2k + j)
        float le8[8], ri8[8];
#pragma unroll
        for (int k = 0; k < 8; ++k) {
            const f32x4 v = R[2 * k + j];
            // left = x[.., w0-1] from lane w4-1 (.w); cross-parity leak lands
            // exactly on masked w4==0 / w4==31 lanes (the pad-zero positions)
            float l_ = __shfl_up(v.w, 1, 64);
            float r_ = __shfl_down(v.x, 1, 64);
            if (w4 == 0)  l_ = 0.f;
            if (w4 == 31) r_ = 0.f;
            le8[k] = l_;  ri8[k] = r_;
        }
#pragma unroll
        for (int l = 0; l < 3; ++l) {
            float* p = dst0 + (size_t)(j * 3 + l) * CHW;
#pragma unroll
            for (int k = 0; k < 8; ++k) {
                const f32x4 v = R[2 * k + j];
                f32x4 o;
                if (l == 0)      o = (f32x4){le8[k], v.x, v.y, v.z};
                else if (l == 1) o = v;
                else             o = (f32x4){v.y, v.z, v.w, ri8[k]};
                // k*256 floats = 2 rows = 1KB contiguous per wave-store
                __builtin_nontemporal_store(o, reinterpret_cast<f32x4*>(p + k * 256));
            }
        }
    }
}

extern "C" void kernel_launch(void* const* d_in, const int* in_sizes, int n_in,
                              void* d_out, int out_size, void* d_ws, size_t ws_size,
                              hipStream_t stream) {
    const float* x = (const float*)d_in[0];
    float* out = (float*)d_out;

    // 144 (bc,i,hhalf,dsub) groups x 8 d-chunks = 1152 blocks of 256 threads
    dim3 grid(1152, 1, 1);
    dim3 block(256, 1, 1);
    patch3d_kernel<<<grid, block, 0, stream>>>(x, out);
}